// Round 7
// baseline (164.519 us; speedup 1.0000x reference)
//
#include <hip/hip_runtime.h>

#define NN   50000
#define NE   200000
#define INC  16
#define HIDC 32
#define EDGED 8
#define OUTC 32
#define MLPH 128
#define NACT 32

#define NPART 196   // ceil(NN / 256)
#define NODE_T 64

// ---- prep: transpose We [8][512] -> We_t [512][8] ----
__global__ __launch_bounds__(256) void transpose_we(const float* __restrict__ We,
                                                    float* __restrict__ We_t) {
    int idx = blockIdx.x * blockDim.x + threadIdx.x;
    if (idx < EDGED * INC * HIDC) {
        int d = idx / (INC * HIDC), ih = idx % (INC * HIDC);
        We_t[ih * EDGED + d] = We[idx];
    }
}

// ---- degree histogram ----
__global__ __launch_bounds__(256) void hist_kernel(const int* __restrict__ edst,
                                                   int* __restrict__ deg) {
    int e = blockIdx.x * blockDim.x + threadIdx.x;
    if (e < NE) atomicAdd(&deg[edst[e]], 1);
}

// ---- scan pass 1: per-block sums ----
__global__ __launch_bounds__(256) void partial_kernel(const int* __restrict__ deg,
                                                      int* __restrict__ partials) {
    __shared__ int sm[256];
    int t = threadIdx.x, i = blockIdx.x * 256 + t;
    sm[t] = (i < NN) ? deg[i] : 0;
    __syncthreads();
    #pragma unroll
    for (int off = 128; off > 0; off >>= 1) {
        if (t < off) sm[t] += sm[t + off];
        __syncthreads();
    }
    if (t == 0) partials[blockIdx.x] = sm[0];
}

// ---- scan pass 2: exclusive scan of 196 partials ----
__global__ __launch_bounds__(256) void scan_partials_kernel(const int* __restrict__ partials,
                                                            int* __restrict__ poff) {
    __shared__ int sm[256];
    int t = threadIdx.x;
    sm[t] = (t < NPART) ? partials[t] : 0;
    __syncthreads();
    for (int off = 1; off < 256; off <<= 1) {
        int v = (t >= off) ? sm[t - off] : 0;
        __syncthreads();
        sm[t] += v;
        __syncthreads();
    }
    poff[t] = (t == 0) ? 0 : sm[t - 1];
}

// ---- scan pass 3: block-local scan + base -> row_off ----
__global__ __launch_bounds__(256) void rowoff_kernel(const int* __restrict__ deg,
                                                     const int* __restrict__ poff,
                                                     int* __restrict__ row_off) {
    __shared__ int sm[256];
    int t = threadIdx.x, i = blockIdx.x * 256 + t;
    int d = (i < NN) ? deg[i] : 0;
    sm[t] = d;
    __syncthreads();
    for (int off = 1; off < 256; off <<= 1) {
        int v = (t >= off) ? sm[t - off] : 0;
        __syncthreads();
        sm[t] += v;
        __syncthreads();
    }
    int excl = sm[t] - d + poff[blockIdx.x];
    if (i < NN) {
        row_off[i] = excl;
        if (i == NN - 1) row_off[NN] = excl + d;   // == NE
    }
}

// ---- edge kernel: one lane per edge; We_t/be staged in LDS (broadcast reads) ----
__global__ __launch_bounds__(256, 4) void edge_kernel(
    const float* __restrict__ x,
    const int*   __restrict__ esrc,
    const int*   __restrict__ edst,
    const float* __restrict__ ea,
    const float* __restrict__ We_t,   // [512][8]
    const float* __restrict__ be,
    const int*   __restrict__ row_off,
    int*         __restrict__ cursor,
    float*       __restrict__ sorted_msg)
{
    __shared__ float sWe[EDGED * INC * HIDC];   // 16 KB, [ih][d]
    __shared__ float sbe[INC * HIDC];           //  2 KB

    {
        float4* d4 = reinterpret_cast<float4*>(sWe);
        const float4* s4 = reinterpret_cast<const float4*>(We_t);
        for (int i = threadIdx.x; i < (EDGED * INC * HIDC) / 4; i += 256) d4[i] = s4[i];
        float4* b4 = reinterpret_cast<float4*>(sbe);
        const float4* t4 = reinterpret_cast<const float4*>(be);
        for (int i = threadIdx.x; i < (INC * HIDC) / 4; i += 256) b4[i] = t4[i];
    }
    __syncthreads();

    int e = blockIdx.x * blockDim.x + threadIdx.x;
    if (e >= NE) return;
    int src = esrc[e];
    int dst = edst[e];

    const float4* ea4 = reinterpret_cast<const float4*>(ea) + (size_t)e * 2;
    float4 ev0 = ea4[0], ev1 = ea4[1];
    float eav[8] = {ev0.x, ev0.y, ev0.z, ev0.w, ev1.x, ev1.y, ev1.z, ev1.w};

    float msg[HIDC];
    #pragma unroll
    for (int h = 0; h < HIDC; ++h) msg[h] = 0.f;

    const float4* x4 = reinterpret_cast<const float4*>(x) + (size_t)src * 4;

    for (int i4 = 0; i4 < 4; ++i4) {
        float4 xv = x4[i4];
        float xs[4] = {xv.x, xv.y, xv.z, xv.w};
        #pragma unroll
        for (int ii = 0; ii < 4; ++ii) {
            int i = i4 * 4 + ii;
            const float* wbase = sWe + i * (HIDC * EDGED);
            const float* becol = sbe + i * HIDC;
            float xi = xs[ii];
            #pragma unroll
            for (int h = 0; h < HIDC; ++h) {
                const float* wr = wbase + h * EDGED;
                float w = becol[h];
                #pragma unroll
                for (int d = 0; d < EDGED; ++d)
                    w = fmaf(eav[d], wr[d], w);
                w = fmaxf(w, 0.f);
                msg[h] = fmaf(xi, w, msg[h]);
            }
        }
    }

    int pos = row_off[dst] + atomicAdd(&cursor[dst], 1);
    float4* mrow = reinterpret_cast<float4*>(sorted_msg) + (size_t)pos * 8;
    #pragma unroll
    for (int h4 = 0; h4 < 8; ++h4)
        mrow[h4] = make_float4(msg[h4 * 4 + 0], msg[h4 * 4 + 1],
                               msg[h4 * 4 + 2], msg[h4 * 4 + 3]);
}

// ---- fused node kernel: 1 thread per node; ALL weights staged in LDS
//      (uniform ds_read_b128 broadcast, deeply pipelinable). ----
// LDS float offsets:
#define S_WROOT 0        // 512
#define S_WLIN  512      // 1024
#define S_WQ1   1536     // 4096  [32][128]
#define S_WQ2   5632     // 4096  [128][32]
#define S_BCONV 9728     // 32
#define S_GAMMA 9760     // 32
#define S_BETA  9792     // 32
#define S_BLIN  9824     // 32
#define S_BQ1   9856     // 128
#define S_BQ2   9984     // 32
#define S_TOT   10016    // floats = 40064 B

__global__ __launch_bounds__(NODE_T, 1) void node_fused_kernel(
    const float* __restrict__ x,
    const float* __restrict__ sorted_msg,
    const int*   __restrict__ row_off,
    const float* __restrict__ Wroot,   // [16][32]
    const float* __restrict__ bconv,
    const float* __restrict__ gamma,
    const float* __restrict__ beta,
    const float* __restrict__ Wlin,    // [32][32]
    const float* __restrict__ blin,
    const float* __restrict__ Wq1,     // [32][128]
    const float* __restrict__ bq1,
    const float* __restrict__ Wq2,     // [128][32]
    const float* __restrict__ bq2,
    float* __restrict__ out)
{
    __shared__ float sm[S_TOT];

    // ---- stage all weights (float4, parallel) ----
    {
        float4* d4 = reinterpret_cast<float4*>(sm);
        const float4* s;
        int t = threadIdx.x;
        s = reinterpret_cast<const float4*>(Wroot);
        for (int i = t; i < 512/4; i += NODE_T) d4[S_WROOT/4 + i] = s[i];
        s = reinterpret_cast<const float4*>(Wlin);
        for (int i = t; i < 1024/4; i += NODE_T) d4[S_WLIN/4 + i] = s[i];
        s = reinterpret_cast<const float4*>(Wq1);
        for (int i = t; i < 4096/4; i += NODE_T) d4[S_WQ1/4 + i] = s[i];
        s = reinterpret_cast<const float4*>(Wq2);
        for (int i = t; i < 4096/4; i += NODE_T) d4[S_WQ2/4 + i] = s[i];
        s = reinterpret_cast<const float4*>(bconv);
        if (t < 8)  d4[S_BCONV/4 + t] = s[t];
        s = reinterpret_cast<const float4*>(gamma);
        if (t < 8)  d4[S_GAMMA/4 + t] = s[t];
        s = reinterpret_cast<const float4*>(beta);
        if (t < 8)  d4[S_BETA/4 + t] = s[t];
        s = reinterpret_cast<const float4*>(blin);
        if (t < 8)  d4[S_BLIN/4 + t] = s[t];
        s = reinterpret_cast<const float4*>(bq1);
        if (t < 32) d4[S_BQ1/4 + t] = s[t];
        s = reinterpret_cast<const float4*>(bq2);
        if (t < 8)  d4[S_BQ2/4 + t] = s[t];
    }
    __syncthreads();

    int n = blockIdx.x * NODE_T + threadIdx.x;
    if (n >= NN) return;

    // ---- h = bconv + sum(msg rows) + x @ Wroot ----
    float h[HIDC];
    #pragma unroll
    for (int c = 0; c < HIDC; ++c) h[c] = sm[S_BCONV + c];

    int start = row_off[n], end = row_off[n + 1];
    for (int k = start; k < end; ++k) {
        const float4* m4 = reinterpret_cast<const float4*>(sorted_msg) + (size_t)k * 8;
        #pragma unroll
        for (int c4 = 0; c4 < 8; ++c4) {
            float4 m = m4[c4];
            h[c4 * 4 + 0] += m.x;
            h[c4 * 4 + 1] += m.y;
            h[c4 * 4 + 2] += m.z;
            h[c4 * 4 + 3] += m.w;
        }
    }

    const float4* x4 = reinterpret_cast<const float4*>(x) + (size_t)n * 4;
    #pragma unroll
    for (int i4 = 0; i4 < 4; ++i4) {
        float4 xv = x4[i4];
        float xs[4] = {xv.x, xv.y, xv.z, xv.w};
        #pragma unroll
        for (int ii = 0; ii < 4; ++ii) {
            const float* wr = sm + S_WROOT + (i4 * 4 + ii) * HIDC;
            float xi = xs[ii];
            #pragma unroll
            for (int c = 0; c < HIDC; ++c)
                h[c] = fmaf(xi, wr[c], h[c]);
        }
    }

    // ---- LayerNorm (two-pass) + ReLU ----
    float mu = 0.f;
    #pragma unroll
    for (int c = 0; c < HIDC; ++c) mu += h[c];
    mu *= (1.f / HIDC);
    float var = 0.f;
    #pragma unroll
    for (int c = 0; c < HIDC; ++c) { float t = h[c] - mu; var = fmaf(t, t, var); }
    var *= (1.f / HIDC);
    float rstd = rsqrtf(var + 1e-5f);
    #pragma unroll
    for (int c = 0; c < HIDC; ++c)
        h[c] = fmaxf(fmaf((h[c] - mu) * rstd, sm[S_GAMMA + c], sm[S_BETA + c]), 0.f);

    // ---- feat = h @ Wlin + blin ----
    float f[OUTC];
    #pragma unroll
    for (int a = 0; a < OUTC; ++a) f[a] = sm[S_BLIN + a];
    #pragma unroll
    for (int k = 0; k < HIDC; ++k) {
        float hk = h[k];
        const float* wr = sm + S_WLIN + k * OUTC;
        #pragma unroll
        for (int a = 0; a < OUTC; ++a)
            f[a] = fmaf(hk, wr[a], f[a]);
    }

    // ---- q_head in 4 m-chunks of 32 ----
    float q[NACT];
    #pragma unroll
    for (int a = 0; a < NACT; ++a) q[a] = sm[S_BQ2 + a];

    for (int c = 0; c < 4; ++c) {
        const float* w1c = sm + S_WQ1 + c * 32;    // [k][c*32+j]
        const float* b1c = sm + S_BQ1 + c * 32;
        const float* w2c = sm + S_WQ2 + c * 32 * NACT;

        float acc[32];
        #pragma unroll
        for (int j = 0; j < 32; ++j) acc[j] = b1c[j];

        #pragma unroll
        for (int k = 0; k < 32; ++k) {
            float fk = f[k];
            const float* wr = w1c + k * MLPH;
            #pragma unroll
            for (int j = 0; j < 32; ++j)
                acc[j] = fmaf(fk, wr[j], acc[j]);
        }

        #pragma unroll
        for (int j = 0; j < 32; ++j) {
            float t = fmaxf(acc[j], 0.f);
            const float* wr = w2c + j * NACT;
            #pragma unroll
            for (int a = 0; a < NACT; ++a)
                q[a] = fmaf(t, wr[a], q[a]);
        }
    }

    float4* o4 = reinterpret_cast<float4*>(out) + (size_t)n * 8;
    #pragma unroll
    for (int a4 = 0; a4 < 8; ++a4)
        o4[a4] = make_float4(q[a4 * 4 + 0], q[a4 * 4 + 1], q[a4 * 4 + 2], q[a4 * 4 + 3]);
}

extern "C" void kernel_launch(void* const* d_in, const int* in_sizes, int n_in,
                              void* d_out, int out_size, void* d_ws, size_t ws_size,
                              hipStream_t stream) {
    const float* x     = (const float*)d_in[0];
    const int*   esrc  = (const int*)d_in[1];
    const int*   edst  = (const int*)d_in[2];
    const float* ea    = (const float*)d_in[3];
    const float* We    = (const float*)d_in[4];
    const float* be    = (const float*)d_in[5];
    const float* Wroot = (const float*)d_in[6];
    const float* bconv = (const float*)d_in[7];
    const float* gamma = (const float*)d_in[8];
    const float* beta  = (const float*)d_in[9];
    const float* Wlin  = (const float*)d_in[10];
    const float* blin  = (const float*)d_in[11];
    const float* Wq1   = (const float*)d_in[12];
    const float* bq1   = (const float*)d_in[13];
    const float* Wq2   = (const float*)d_in[14];
    const float* bq2   = (const float*)d_in[15];
    float* out = (float*)d_out;

    // workspace layout
    char* ws = (char*)d_ws;
    float* We_t       = (float*)(ws + 0);         //  16 KB
    int*   deg        = (int*)(ws + 16384);       // 200704 B
    int*   cursor     = (int*)(ws + 217088);      // 200704 B
    int*   row_off    = (int*)(ws + 417792);      // 201728 B
    int*   partials   = (int*)(ws + 619520);      // 1 KB
    int*   poff       = (int*)(ws + 620544);      // 1 KB
    float* sorted_msg = (float*)(ws + 621568);    // 25.6 MB

    hipMemsetAsync(deg, 0, 2 * 200704, stream);   // deg + cursor (adjacent)

    transpose_we<<<16, 256, 0, stream>>>(We, We_t);
    hist_kernel<<<(NE + 255) / 256, 256, 0, stream>>>(edst, deg);
    partial_kernel<<<NPART, 256, 0, stream>>>(deg, partials);
    scan_partials_kernel<<<1, 256, 0, stream>>>(partials, poff);
    rowoff_kernel<<<NPART, 256, 0, stream>>>(deg, poff, row_off);
    edge_kernel<<<(NE + 255) / 256, 256, 0, stream>>>(x, esrc, edst, ea, We_t, be,
                                                      row_off, cursor, sorted_msg);
    node_fused_kernel<<<(NN + NODE_T - 1) / NODE_T, NODE_T, 0, stream>>>(
        x, sorted_msg, row_off, Wroot, bconv, gamma, beta,
        Wlin, blin, Wq1, bq1, Wq2, bq2, out);
}